// Round 5
// baseline (273.923 us; speedup 1.0000x reference)
//
#include <hip/hip_runtime.h>
#include <hip/hip_bf16.h>
#include <stdint.h>

#define B_   4
#define S_   2048
#define H_   16
#define HD_  64
#define D_   1024

typedef short  short8  __attribute__((ext_vector_type(8)));
typedef float  f32x4   __attribute__((ext_vector_type(4)));
typedef float  f32x16  __attribute__((ext_vector_type(16)));

__device__ __forceinline__ unsigned short f2bf(float f) {
    union { float f; unsigned u; } v; v.f = f;
    unsigned r = v.u + 0x7fffu + ((v.u >> 16) & 1u);
    return (unsigned short)(r >> 16);
}

#if __has_builtin(__builtin_amdgcn_exp2f)
#define EXP2(x) __builtin_amdgcn_exp2f(x)
#else
#define EXP2(x) exp2f(x)
#endif

__device__ __forceinline__ unsigned cvtpk(float lo, float hi) {
    unsigned r;
    asm("v_cvt_pk_bf16_f32 %0, %1, %2" : "=v"(r) : "v"(lo), "v"(hi));
    return r;
}

__device__ __forceinline__ float bq(float v, int srclane) {
    return __int_as_float(__builtin_amdgcn_ds_bpermute(srclane << 2, __float_as_int(v)));
}

#define MFMA32(a, b, c) __builtin_amdgcn_mfma_f32_32x32x16_bf16(a, b, c, 0, 0, 0)

// ---------------- fp32 -> bf16 convert (vectorized) ----------------
__global__ __launch_bounds__(256) void k_cvt(const float* __restrict__ in,
                                             unsigned short* __restrict__ out) {
    int i = (blockIdx.x * 256 + threadIdx.x) * 4;
    float4 f = *(const float4*)(in + i);
    ushort4 o;
    o.x = f2bf(f.x); o.y = f2bf(f.y); o.z = f2bf(f.z); o.w = f2bf(f.w);
    *(ushort4*)(out + i) = o;
}

// ---------- transpose + convert: in[K][N] f32 -> out[N][K] bf16 ----------
__global__ __launch_bounds__(256) void k_transpose_cvt(const float* __restrict__ in,
                                                       unsigned short* __restrict__ out,
                                                       int K, int N) {
    __shared__ float tile[32][33];
    int n0 = blockIdx.x * 32, k0 = blockIdx.y * 32;
    int tx = threadIdx.x, ty = threadIdx.y;
#pragma unroll
    for (int i = 0; i < 32; i += 8)
        tile[ty + i][tx] = in[(size_t)(k0 + ty + i) * N + n0 + tx];
    __syncthreads();
#pragma unroll
    for (int i = 0; i < 32; i += 8)
        out[(size_t)(n0 + ty + i) * K + k0 + tx] = f2bf(tile[tx][ty + i]);
}

__device__ __forceinline__ void async_load16(const unsigned short* g, unsigned short* l) {
    __builtin_amdgcn_global_load_lds(
        (const __attribute__((address_space(1))) unsigned int*)g,
        (__attribute__((address_space(3))) unsigned int*)l, 16, 0, 0);
}

// ---------------- bf16 GEMM: C[m][n] = A[m][k] * BT[n][k] + bias ----------------
// EPI 0: scatter to Q (scaled by 0.125*log2(e)), K [B,H,S,64], V^T [B,H,64,S]
// EPI 1: fp32 output += bias
template <int EPI>
__global__ __launch_bounds__(256) void k_gemm(const unsigned short* __restrict__ A,
                                              const unsigned short* __restrict__ BT,
                                              const float* __restrict__ bias,
                                              float* __restrict__ outf,
                                              unsigned short* __restrict__ qb,
                                              unsigned short* __restrict__ kb,
                                              unsigned short* __restrict__ vtb,
                                              int M, int N, int K) {
    __shared__ __attribute__((aligned(16))) unsigned short As[128 * 32];
    __shared__ __attribute__((aligned(16))) unsigned short Bs[128 * 32];
    const int tid = threadIdx.x, wave = tid >> 6, lane = tid & 63;
    const int m0 = blockIdx.y * 128, n0 = blockIdx.x * 128;
    const int wr = wave >> 1, wc = wave & 1;

    f32x4 acc[4][4] = {};

    for (int kt = 0; kt < K; kt += 32) {
#pragma unroll
        for (int p = 0; p < 2; p++) {
            int chunk = p * 4 + wave;
            int off   = chunk * 1024 + lane * 16;
            int row   = off >> 6;
            int col   = (off & 63) >> 1;
            async_load16(A  + (size_t)(m0 + row) * K + kt + col, As + chunk * 512);
            async_load16(BT + (size_t)(n0 + row) * K + kt + col, Bs + chunk * 512);
        }
        __syncthreads();
        short8 af[4], bf[4];
#pragma unroll
        for (int i = 0; i < 4; i++) {
            af[i] = *(const short8*)(As + (wr * 64 + i * 16 + (lane & 15)) * 32 + (lane >> 4) * 8);
            bf[i] = *(const short8*)(Bs + (wc * 64 + i * 16 + (lane & 15)) * 32 + (lane >> 4) * 8);
        }
#pragma unroll
        for (int i = 0; i < 4; i++)
#pragma unroll
            for (int j = 0; j < 4; j++)
                acc[i][j] = __builtin_amdgcn_mfma_f32_16x16x32_bf16(af[i], bf[j], acc[i][j], 0, 0, 0);
        __syncthreads();
    }

#pragma unroll
    for (int i = 0; i < 4; i++) {
#pragma unroll
        for (int j = 0; j < 4; j++) {
            int n = n0 + wc * 64 + j * 16 + (lane & 15);
            float bv = bias[n];
#pragma unroll
            for (int r = 0; r < 4; r++) {
                int m = m0 + wr * 64 + i * 16 + ((lane >> 4) << 2) + r;
                float val = acc[i][j][r] + bv;
                if (EPI == 0) {
                    int part = n >> 10, rem = n & 1023;
                    int h = rem >> 6, d = rem & 63;
                    int b = m >> 11, s = m & 2047;
                    size_t bh = (size_t)(b * 16 + h);
                    // fold 1/sqrt(64) and log2(e) into Q so softmax runs in exp2 domain
                    if (part == 0)      qb[(bh * S_ + s) * HD_ + d] = f2bf(val * 0.18033688011112042f);
                    else if (part == 1) kb[(bh * S_ + s) * HD_ + d] = f2bf(val);
                    else                vtb[(bh * HD_ + d) * S_ + s] = f2bf(val);
                } else {
                    outf[(size_t)m * N + n] = val;
                }
            }
        }
    }
}

// ---------------- causal flash attention: intra-block split-KV ----------------
// grid: 4096 blocks (bh x strip), block 256 = 4 waves.
// Each block owns one 32-row q-strip; the KV prefix is split into 4 contiguous
// quarters, one per wave (longest wave chain 64 -> 16 iters). Per-wave online
// softmax runs in registers (swapped QK^T, verified 32x32 layouts); partial
// O/m/l merge through LDS with weights applied in the q-indexed combine domain.
__global__ __launch_bounds__(256) void k_attn(const unsigned short* __restrict__ Qg,
                                              const unsigned short* __restrict__ Kg,
                                              const unsigned short* __restrict__ Vt,
                                              unsigned short* __restrict__ Z) {
    __shared__ float OL[4][32][68];   // +4 pad spreads banks
    __shared__ float mL[4][32];
    __shared__ float lL[4][32];

    const int i = blockIdx.x;
    const int bh = (i & 7) * 8 + ((i >> 3) & 7);   // 8 bh per XCD -> K/V in one L2
    const int strip = 63 - (i >> 6);               // longest strips launch first
    const int tid = threadIdx.x, wave = tid >> 6, lane = tid & 63;
    const int c = lane & 31, hi = lane >> 5;
    const int qbase = strip * 32;
    const int b = bh >> 4, h = bh & 15;

    const int nkv = strip + 1;              // 32-t tiles in causal prefix
    const int per = (nkv + 3) >> 2;
    const int tbeg = wave * per;
    const int tend0 = tbeg + per;
    const int tend = tend0 < nkv ? tend0 : nkv;

    const unsigned short* Qb = Qg + ((size_t)bh * S_ + qbase + c) * HD_ + hi * 8;
    const unsigned short* Kb = Kg + ((size_t)bh * S_ + c) * HD_ + hi * 8;
    const unsigned short* Vb = Vt + ((size_t)bh * HD_ + c) * S_ + hi * 8;

    f32x16 oacc[2] = {};                 // O[q=crow(r,hi)][d = dt*32 + c]
    float m_r = -1e30f, l_r = 0.f;

    if (tbeg < tend) {
        short8 qf[4];
#pragma unroll
        for (int kd = 0; kd < 4; kd++)
            qf[kd] = *(const short8*)(Qb + kd * 16);

        short8 kf_cur[4], kf_nxt[4];
#pragma unroll
        for (int kd = 0; kd < 4; kd++)
            kf_cur[kd] = *(const short8*)(Kb + (size_t)(tbeg * 32) * HD_ + kd * 16);

        for (int tt = tbeg; tt < tend; tt++) {
            const int t0 = tt * 32;
            const int tn = (tt + 1 < tend) ? (t0 + 32) : t0;   // clamped prefetch
#pragma unroll
            for (int kd = 0; kd < 4; kd++)
                kf_nxt[kd] = *(const short8*)(Kb + (size_t)tn * HD_ + kd * 16);

            f32x16 sT = {};              // sT[t=crow(r,hi)][q=c]
#pragma unroll
            for (int kd = 0; kd < 4; kd++)
                sT = MFMA32(kf_cur[kd], qf[kd], sT);

            short8 vf[2][2];             // B[col=d=dt*32+c][k=t=ks*16+hi*8+j]
#pragma unroll
            for (int dt = 0; dt < 2; dt++)
#pragma unroll
                for (int ks = 0; ks < 2; ks++)
                    vf[dt][ks] = *(const short8*)(Vb + (size_t)(dt * 32) * S_ + t0 + ks * 16);

            if (t0 == qbase) {           // diagonal tile: mask t_local > q_local
#pragma unroll
                for (int r = 0; r < 16; r++) {
                    int tl = (r & 3) + 8 * (r >> 2) + 4 * hi;
                    if (tl > c) sT[r] = -1e30f;
                }
            }

            // depth-4 max tree + cross-half
            float a0 = fmaxf(sT[0], sT[8]),  a1 = fmaxf(sT[1], sT[9]);
            float a2 = fmaxf(sT[2], sT[10]), a3 = fmaxf(sT[3], sT[11]);
            float a4 = fmaxf(sT[4], sT[12]), a5 = fmaxf(sT[5], sT[13]);
            float a6 = fmaxf(sT[6], sT[14]), a7 = fmaxf(sT[7], sT[15]);
            a0 = fmaxf(a0, a4); a1 = fmaxf(a1, a5); a2 = fmaxf(a2, a6); a3 = fmaxf(a3, a7);
            float mx = fmaxf(fmaxf(a0, a2), fmaxf(a1, a3));
            mx = fmaxf(mx, __shfl_xor(mx, 32));

            // defer-max: rescale only when max grows by > 8 (exp2 domain)
            if (!__all(mx <= m_r + 8.f)) {
                float mn = fmaxf(m_r, mx);
                float ps = EXP2(m_r - mn);
                m_r = mn;
                l_r *= ps;
#pragma unroll
                for (int r = 0; r < 16; r++) {
                    float psb = bq(ps, (r & 3) + 8 * (r >> 2) + 4 * hi);
                    oacc[0][r] *= psb;
                    oacc[1][r] *= psb;
                }
            }
#pragma unroll
            for (int r = 0; r < 16; r++)
                sT[r] = EXP2(sT[r] - m_r);
            // depth-4 sum tree
            float s0 = sT[0] + sT[8],  s1 = sT[1] + sT[9];
            float s2 = sT[2] + sT[10], s3 = sT[3] + sT[11];
            float s4 = sT[4] + sT[12], s5 = sT[5] + sT[13];
            float s6 = sT[6] + sT[14], s7 = sT[7] + sT[15];
            s0 += s4; s1 += s5; s2 += s6; s3 += s7;
            float rs = (s0 + s2) + (s1 + s3);
            rs += __shfl_xor(rs, 32);
            l_r += rs;

            // pack P to bf16 pairs (t-pairs within 8-blocks), then cross-half exchange
            unsigned pk0 = cvtpk(sT[0],  sT[1]);
            unsigned pk1 = cvtpk(sT[2],  sT[3]);
            unsigned pk2 = cvtpk(sT[4],  sT[5]);
            unsigned pk3 = cvtpk(sT[6],  sT[7]);
            unsigned pk4 = cvtpk(sT[8],  sT[9]);
            unsigned pk5 = cvtpk(sT[10], sT[11]);
            unsigned pk6 = cvtpk(sT[12], sT[13]);
            unsigned pk7 = cvtpk(sT[14], sT[15]);
            unsigned q0 = (unsigned)__shfl_xor((int)pk0, 32);
            unsigned q1 = (unsigned)__shfl_xor((int)pk1, 32);
            unsigned q2 = (unsigned)__shfl_xor((int)pk2, 32);
            unsigned q3 = (unsigned)__shfl_xor((int)pk3, 32);
            unsigned q4 = (unsigned)__shfl_xor((int)pk4, 32);
            unsigned q5 = (unsigned)__shfl_xor((int)pk5, 32);
            unsigned q6 = (unsigned)__shfl_xor((int)pk6, 32);
            unsigned q7 = (unsigned)__shfl_xor((int)pk7, 32);
            union { unsigned u[4]; short8 s; } pa0, pa1;
            // A-frag word j holds t = 8*hi + 2j, 8*hi + 2j+1 (ks*16 block offset)
            pa0.u[0] = hi ? q2 : pk0;  pa0.u[1] = hi ? q3 : pk1;
            pa0.u[2] = hi ? pk2 : q0;  pa0.u[3] = hi ? pk3 : q1;
            pa1.u[0] = hi ? q6 : pk4;  pa1.u[1] = hi ? q7 : pk5;
            pa1.u[2] = hi ? pk6 : q4;  pa1.u[3] = hi ? pk7 : q5;

            oacc[0] = MFMA32(pa0.s, vf[0][0], oacc[0]);
            oacc[1] = MFMA32(pa0.s, vf[1][0], oacc[1]);
            oacc[0] = MFMA32(pa1.s, vf[0][1], oacc[0]);
            oacc[1] = MFMA32(pa1.s, vf[1][1], oacc[1]);

#pragma unroll
            for (int kd = 0; kd < 4; kd++)
                kf_cur[kd] = kf_nxt[kd];
        }
    }

    // dump raw partials to LDS
    if (hi == 0) { mL[wave][c] = m_r; lL[wave][c] = l_r; }
#pragma unroll
    for (int r = 0; r < 16; r++) {
        int crow = (r & 3) + 8 * (r >> 2) + 4 * hi;
        OL[wave][crow][c]      = oacc[0][r];
        OL[wave][crow][32 + c] = oacc[1][r];
    }
    __syncthreads();

    // combine: thread -> (q = tid>>3, d0 = (tid&7)*8); weights in q-domain (no bpermute)
    const int q = tid >> 3, d0 = (tid & 7) * 8;
    float m0v = mL[0][q], m1v = mL[1][q], m2v = mL[2][q], m3v = mL[3][q];
    float M = fmaxf(fmaxf(m0v, m1v), fmaxf(m2v, m3v));
    float w0 = EXP2(m0v - M), w1 = EXP2(m1v - M), w2 = EXP2(m2v - M), w3 = EXP2(m3v - M);
    float lf = w0 * lL[0][q] + w1 * lL[1][q] + w2 * lL[2][q] + w3 * lL[3][q];
    float inv = __builtin_amdgcn_rcpf(lf);
    union { unsigned short u[8]; ushort4 v[2]; } zo;
#pragma unroll
    for (int d = 0; d < 8; d++) {
        float o = w0 * OL[0][q][d0 + d] + w1 * OL[1][q][d0 + d]
                + w2 * OL[2][q][d0 + d] + w3 * OL[3][q][d0 + d];
        zo.u[d] = f2bf(o * inv);
    }
    unsigned short* zp = Z + ((size_t)b * S_ + qbase + q) * D_ + h * HD_ + d0;
    *(ushort4*)zp       = zo.v[0];
    *(ushort4*)(zp + 4) = zo.v[1];
}

extern "C" void kernel_launch(void* const* d_in, const int* in_sizes, int n_in,
                              void* d_out, int out_size, void* d_ws, size_t ws_size,
                              hipStream_t stream) {
    const float* x     = (const float*)d_in[0];
    const float* w_qkv = (const float*)d_in[1];
    const float* b_qkv = (const float*)d_in[2];
    const float* w_out = (const float*)d_in[3];
    const float* b_out = (const float*)d_in[4];
    float* out = (float*)d_out;

    char* ws = (char*)d_ws;
    unsigned short* xb    = (unsigned short*)(ws + 0);          // 16 MB (aliased as Z later)
    unsigned short* wqkvT = (unsigned short*)(ws + 16777216);   // 6 MB
    unsigned short* woutT = (unsigned short*)(ws + 23068672);   // 2 MB
    unsigned short* qb    = (unsigned short*)(ws + 25165824);   // 16 MB
    unsigned short* kb    = (unsigned short*)(ws + 41943040);   // 16 MB
    unsigned short* vtb   = (unsigned short*)(ws + 58720256);   // 16 MB
    unsigned short* zb    = xb;  // safe alias: xb consumed by QKV GEMM before attn writes zb

    k_cvt<<<8192, 256, 0, stream>>>(x, xb);
    k_transpose_cvt<<<dim3(96, 32), dim3(32, 8), 0, stream>>>(w_qkv, wqkvT, 1024, 3072);
    k_transpose_cvt<<<dim3(32, 32), dim3(32, 8), 0, stream>>>(w_out, woutT, 1024, 1024);
    k_gemm<0><<<dim3(24, 64), 256, 0, stream>>>(xb, wqkvT, b_qkv, nullptr, qb, kb, vtb,
                                                8192, 3072, 1024);
    k_attn<<<4096, 256, 0, stream>>>(qb, kb, vtb, zb);
    k_gemm<1><<<dim3(8, 64), 256, 0, stream>>>(zb, woutT, b_out, out, nullptr, nullptr, nullptr,
                                               8192, 1024, 1024);
}